// Round 4
// baseline (390.737 us; speedup 1.0000x reference)
//
#include <hip/hip_runtime.h>

#define T_STEPS 512
#define HSTR 80        // _Float16 per h batch-row (160 B)
#define XSTRIDE 520    // _Float16 per x-row
#define OSTRIDE 513    // floats per out-row
#define NB 4           // batches per block; 512 blocks = 2 blocks/CU

typedef _Float16 half8v __attribute__((ext_vector_type(8)));
typedef _Float16 half4v __attribute__((ext_vector_type(4)));
typedef _Float16 half2v __attribute__((ext_vector_type(2)));
typedef float f32x4 __attribute__((ext_vector_type(4)));

#define K1 1.442695041f    // log2(e)
#define K2 2.885390082f    // 2*log2(e)

__device__ __forceinline__ float ex2(float x) {
#if __has_builtin(__builtin_amdgcn_exp2f)
    return __builtin_amdgcn_exp2f(x);
#else
    return exp2f(x);
#endif
}
__device__ __forceinline__ float rcp_fast(float x) {
#if __has_builtin(__builtin_amdgcn_rcpf)
    return __builtin_amdgcn_rcpf(x);
#else
    return 1.0f / x;
#endif
}

// fused LSTM cell activation; args prescaled by -log2e (i,f,o) / 2log2e (g)
__device__ __forceinline__ float lstm_act(float v0, float v1, float v2, float v3,
                                          float& cs) {
    float A  = ex2(v0);                   // e^{-i}
    float Bt = ex2(v2);                   // e^{2g}
    float ig = (Bt - 1.0f) * rcp_fast((1.0f + A) * (1.0f + Bt));
    float rf = rcp_fast(1.0f + ex2(v1));  // sig(f)
    cs = fmaf(cs, rf, ig);
    float cc = fminf(fmaxf(cs, -15.f), 15.f);
    float Ao = ex2(v3);                   // e^{-o}
    float C  = ex2(cc * K2);              // e^{2c}
    return (C - 1.0f) * rcp_fast((1.0f + Ao) * (1.0f + C));
}

// partial fc-dot over this lane's A-frag slice (f16), reduced over the 4 k-quads
__device__ __forceinline__ float out_dot(half8v a0, half8v a1,
                                         const float* wfc0, const float* wfc1) {
    float s = 0.f;
#pragma unroll
    for (int j = 0; j < 8; ++j) s = fmaf((float)a0[j], wfc0[j], s);
#pragma unroll
    for (int j = 0; j < 8; ++j) s = fmaf((float)a1[j], wfc1[j], s);
    s += __shfl_xor(s, 16);
    s += __shfl_xor(s, 32);
    return s;   // full 64-dot for batch (c>>2), on all lanes
}

// R14: 2-wave blocks. Barrier rendezvous narrowed 4->2 waves; 2 blocks/CU
// -> 1 wave/SIMD (private matrix+VALU pipes, no cross-chain contention).
// Each wave covers 2 unit-groups: tiles (n=class, ui=0/1), cols = units
// 32w+16ui+c, so 16 MFMAs/wave/step. A-frag (row c -> batch c>>2) unchanged
// and shared across all 8 tiles. Lane (q,c) acts batch q, units 32w+c and
// 32w+16+c (2 chains, all lanes active). fc-dot rotates over the 2 waves.
__global__ __launch_bounds__(128, 1) void lstm_kernel(
    const float* __restrict__ x, const float* __restrict__ w_ih,
    const float* __restrict__ w_hh, const float* __restrict__ b_ih,
    const float* __restrict__ b_hh, const float* __restrict__ w_fc,
    const float* __restrict__ b_fc, float* __restrict__ out)
{
    __shared__ __align__(16) _Float16 hbuf[2][NB * HSTR];   // 1.3 KB
    __shared__ __align__(16) _Float16 xls[NB * XSTRIDE];    // 4.2 KB
    __shared__ __align__(16) float ols[NB * OSTRIDE];       // 8.2 KB

    const int tid  = threadIdx.x;
    const int w    = tid >> 6;        // wave 0..1
    const int lane = tid & 63;
    const int q    = lane >> 4;       // quad (A k-group / D row-group)
    const int c    = lane & 15;       // unit-in-tile / A-row
    const int b0   = blockIdx.x * NB;

    // ---- stage x: global -> LDS (f16), coalesced float4 reads ----
    for (int i = tid; i < NB * 128; i += 128) {      // 4 rows x 128 float4
        int b  = i >> 7;
        int t4 = i & 127;
        float4 v = *(const float4*)(x + (size_t)(b0 + b) * T_STEPS + t4 * 4);
        half4v hv;
        hv[0] = (_Float16)v.x; hv[1] = (_Float16)v.y;
        hv[2] = (_Float16)v.z; hv[3] = (_Float16)v.w;
        *(half4v*)(&xls[b * XSTRIDE + t4 * 4]) = hv;
    }
    // zero both h buffers (h_{-1} = 0)
    for (int i = tid; i < 2 * NB * HSTR / 2; i += 128) ((int*)hbuf)[i] = 0;

    // ---- B fragments (prescaled): tile (n = gate class, ui = unit-group) ----
    // lane (q,c): B[k=32kk+8q+jj][col c] = sK[n]*w_hh[g][k], g = 64n+32w+16ui+c
    const float sK[4] = { -K1, -K1, K2, -K1 };   // i,f sig; g tanh; o sig
    half8v bfrag[4][2][2];
    float biasS[4][2], wihS[4][2];
#pragma unroll
    for (int n = 0; n < 4; ++n) {
#pragma unroll
        for (int ui = 0; ui < 2; ++ui) {
            int g = 64 * n + 32 * w + 16 * ui + c;
            biasS[n][ui] = (b_ih[g] + b_hh[g]) * sK[n];
            wihS[n][ui]  = w_ih[g] * sK[n];
#pragma unroll
            for (int kk = 0; kk < 2; ++kk) {
                const float* wp = w_hh + g * 64 + 32 * kk + 8 * q;
                float4 lo  = *(const float4*)(wp);
                float4 hi4 = *(const float4*)(wp + 4);
                half8v f;
                f[0] = (_Float16)(lo.x  * sK[n]); f[1] = (_Float16)(lo.y  * sK[n]);
                f[2] = (_Float16)(lo.z  * sK[n]); f[3] = (_Float16)(lo.w  * sK[n]);
                f[4] = (_Float16)(hi4.x * sK[n]); f[5] = (_Float16)(hi4.y * sK[n]);
                f[6] = (_Float16)(hi4.z * sK[n]); f[7] = (_Float16)(hi4.w * sK[n]);
                bfrag[n][ui][kk] = f;
            }
        }
    }

    // fc weights aligned to this lane's A-frag k-slice
    float wfc0[8], wfc1[8];
#pragma unroll
    for (int j = 0; j < 8; ++j) { wfc0[j] = w_fc[8 * q + j]; wfc1[j] = w_fc[32 + 8 * q + j]; }
    const float bfc = b_fc[0];

    float cs0 = 0.f, cs1 = 0.f;   // cell state: (batch q, unit 32w+c / 32w+16+c)
    const f32x4 zeroq = {0.f, 0.f, 0.f, 0.f};

    __syncthreads();

    half8v sa0 = {}, sa1 = {};  // saved A-frags for rotated fc-dot

    for (int tq = 0; tq < 256; ++tq) {
        // x for this lane's own batch (q), 2 steps (broadcast read)
        half2v xh = *(const half2v*)(&xls[q * XSTRIDE + 2 * tq]);

#pragma unroll
        for (int dt = 0; dt < 2; ++dt) {
            const int t  = 2 * tq + dt;
            const int rb = t & 1;

            // A-frags: A[m][k] = h[m>>2][k]; shared by all 8 tiles
            const _Float16* hp = hbuf[rb] + (c >> 2) * HSTR + 8 * q;
            half8v a0 = *(const half8v*)(hp);        // k = 8q+j
            half8v a1 = *(const half8v*)(hp + 32);   // k = 32+8q+j

            if (dt == w) { sa0 = a0; sa1 = a1; }     // rotate fc-dot ownership

            // scalar x*wih+bias for both owned units (off critical path)
            const float xv = (float)xh[dt];
            float xb[4][2];
#pragma unroll
            for (int n = 0; n < 4; ++n) {
                xb[n][0] = fmaf(xv, wihS[n][0], biasS[n][0]);
                xb[n][1] = fmaf(xv, wihS[n][1], biasS[n][1]);
            }

            _Float16* hwr = hbuf[rb ^ 1];

            // unit-group 0: 4 class tiles (K=64 chained pairs) -> act chain 0
            f32x4 acc0[4];
#pragma unroll
            for (int n = 0; n < 4; ++n) {
                acc0[n] = __builtin_amdgcn_mfma_f32_16x16x32_f16(a1, bfrag[n][0][1], zeroq, 0, 0, 0);
                acc0[n] = __builtin_amdgcn_mfma_f32_16x16x32_f16(a0, bfrag[n][0][0], acc0[n], 0, 0, 0);
            }
            {
                float h0 = lstm_act(acc0[0][0] + xb[0][0], acc0[1][0] + xb[1][0],
                                    acc0[2][0] + xb[2][0], acc0[3][0] + xb[3][0], cs0);
                hwr[q * HSTR + 32 * w + c] = (_Float16)h0;
            }

            // unit-group 1 (MFMAs overlap act chain 0: independent pipes)
            f32x4 acc1[4];
#pragma unroll
            for (int n = 0; n < 4; ++n) {
                acc1[n] = __builtin_amdgcn_mfma_f32_16x16x32_f16(a1, bfrag[n][1][1], zeroq, 0, 0, 0);
                acc1[n] = __builtin_amdgcn_mfma_f32_16x16x32_f16(a0, bfrag[n][1][0], acc1[n], 0, 0, 0);
            }
            {
                float h1 = lstm_act(acc1[0][0] + xb[0][1], acc1[1][0] + xb[1][1],
                                    acc1[2][0] + xb[2][1], acc1[3][0] + xb[3][1], cs1);
                hwr[q * HSTR + 32 * w + 16 + c] = (_Float16)h1;
            }

            __syncthreads();
        }

        // rotated fc-dot: wave w saved A-frags of step st = 2tq+w = h(st-1)
        // -> out column st-1. w=0 covers odd cols, w=1 even cols (0..510).
        {
            int st = 2 * tq + w;
            if (st > 0) {
                float s = out_dot(sa0, sa1, wfc0, wfc1);
                if (lane < 16 && (lane & 3) == 0)
                    ols[(lane >> 2) * OSTRIDE + (st - 1)] = s + bfc;
            }
        }
    }

    // final output column: h_511 lives in hbuf[0] (t=511 wrote rb^1 = 0)
    if (w == 1) {
        const _Float16* hp = hbuf[0] + (c >> 2) * HSTR + 8 * q;
        half8v a0 = *(const half8v*)(hp);
        half8v a1 = *(const half8v*)(hp + 32);
        float s = out_dot(a0, a1, wfc0, wfc1);
        if (lane < 16 && (lane & 3) == 0)
            ols[(lane >> 2) * OSTRIDE + (T_STEPS - 1)] = s + bfc;
    }
    __syncthreads();

    // bulk store: LDS out -> global, coalesced
    for (int i = tid; i < NB * T_STEPS; i += 128) {
        int b = i >> 9;
        int t = i & (T_STEPS - 1);
        out[(size_t)(b0 + b) * T_STEPS + t] = ols[b * OSTRIDE + t];
    }
}

extern "C" void kernel_launch(void* const* d_in, const int* in_sizes, int n_in,
                              void* d_out, int out_size, void* d_ws, size_t ws_size,
                              hipStream_t stream) {
    const float* x    = (const float*)d_in[0];
    const float* w_ih = (const float*)d_in[1];
    const float* w_hh = (const float*)d_in[2];
    const float* b_ih = (const float*)d_in[3];
    const float* b_hh = (const float*)d_in[4];
    const float* w_fc = (const float*)d_in[5];
    const float* b_fc = (const float*)d_in[6];
    float* out = (float*)d_out;
    hipLaunchKernelGGL(lstm_kernel, dim3(2048 / NB), dim3(128), 0, stream,
                       x, w_ih, w_hh, b_ih, b_hh, w_fc, b_fc, out);
}

// Round 5
// 244.685 us; speedup vs baseline: 1.5969x; 1.5969x over previous
//
#include <hip/hip_runtime.h>

#define T_STEPS 512
#define HSTR 80        // _Float16 per h batch-row (160 B)
#define XSTRIDE 520    // _Float16 per x-row
#define OSTRIDE 513    // floats per out-row
#define NB 4           // batches per block; 512 blocks = 2 blocks/CU

typedef _Float16 half8v __attribute__((ext_vector_type(8)));
typedef _Float16 half4v __attribute__((ext_vector_type(4)));
typedef float f32x4 __attribute__((ext_vector_type(4)));

#define K1 1.442695041f    // log2(e)
#define K2 2.885390082f    // 2*log2(e)
#define CZCL 43.28085123f  // 15 * K2 (clamp in cz = cs*K2 domain)

__device__ __forceinline__ float ex2(float x) {
#if __has_builtin(__builtin_amdgcn_exp2f)
    return __builtin_amdgcn_exp2f(x);
#else
    return exp2f(x);
#endif
}
__device__ __forceinline__ float rcp_fast(float x) {
#if __has_builtin(__builtin_amdgcn_rcpf)
    return __builtin_amdgcn_rcpf(x);
#else
    return 1.0f / x;
#endif
}

// partial fc-dot over this lane's A-frag slice (f16), reduced over the 4 k-quads
__device__ __forceinline__ float out_dot(half8v a0, half8v a1,
                                         const float* wfc0, const float* wfc1) {
    float s = 0.f;
#pragma unroll
    for (int j = 0; j < 8; ++j) s = fmaf((float)a0[j], wfc0[j], s);
#pragma unroll
    for (int j = 0; j < 8; ++j) s = fmaf((float)a1[j], wfc1[j], s);
    s += __shfl_xor(s, 16);
    s += __shfl_xor(s, 32);
    return s;   // full 64-dot for batch (c>>2), on all lanes
}

// R15 = R11 champion skeleton + serial-path cuts:
//  (1) cell state kept in cz = cs*K2 domain -> removes the *K2 mul from the
//      post-clamp serial path (C = ex2(clamp(cz))).
//  (2) rotated fc-dot moved INTO the next step's ds_read latency shadow
//      (issued after the A-frag reads, before the dt==w save), instead of
//      serially between the barrier and the reads.
// Topology identical to R11: NB=4, 4 waves, 2 blocks/CU, A rows m -> h[m>>2],
// one act chain per lane (batch q, unit 16w+c), 1 barrier/step.
__global__ __launch_bounds__(256, 2) void lstm_kernel(
    const float* __restrict__ x, const float* __restrict__ w_ih,
    const float* __restrict__ w_hh, const float* __restrict__ b_ih,
    const float* __restrict__ b_hh, const float* __restrict__ w_fc,
    const float* __restrict__ b_fc, float* __restrict__ out)
{
    __shared__ __align__(16) _Float16 hbuf[2][NB * HSTR];   // 1.3 KB
    __shared__ __align__(16) _Float16 xls[NB * XSTRIDE];    // 4.2 KB
    __shared__ __align__(16) float ols[NB * OSTRIDE];       // 8.2 KB

    const int tid  = threadIdx.x;
    const int w    = tid >> 6;        // wave 0..3
    const int lane = tid & 63;
    const int q    = lane >> 4;       // quad (A k-group / D row-group)
    const int c    = lane & 15;       // unit-in-tile / A-row
    const int b0   = blockIdx.x * NB;

    // ---- stage x: global -> LDS (f16), coalesced float4 reads ----
    for (int i = tid; i < NB * 128; i += 256) {      // 4 rows x 128 float4
        int b  = i >> 7;
        int t4 = i & 127;
        float4 v = *(const float4*)(x + (size_t)(b0 + b) * T_STEPS + t4 * 4);
        half4v hv;
        hv[0] = (_Float16)v.x; hv[1] = (_Float16)v.y;
        hv[2] = (_Float16)v.z; hv[3] = (_Float16)v.w;
        *(half4v*)(&xls[b * XSTRIDE + t4 * 4]) = hv;
    }
    // zero both h buffers (h_{-1} = 0)
    for (int i = tid; i < 2 * NB * HSTR / 2; i += 256) ((int*)hbuf)[i] = 0;

    // ---- B fragments (prescaled weights): tile n = gate class ----
    // lane (q,c) holds B[k=32kk+8q+jj][col c] = sK[n]*w_hh[g][k], g = 64n+16w+c
    const float sK[4] = { -K1, -K1, K2, -K1 };   // i,f sig; g tanh; o sig
    half8v bfrag[4][2];
    float biasS[4], wihS[4];
#pragma unroll
    for (int n = 0; n < 4; ++n) {
        int g = 64 * n + 16 * w + c;
        biasS[n] = (b_ih[g] + b_hh[g]) * sK[n];
        wihS[n]  = w_ih[g] * sK[n];
#pragma unroll
        for (int kk = 0; kk < 2; ++kk) {
            const float* wp = w_hh + g * 64 + 32 * kk + 8 * q;
            float4 lo  = *(const float4*)(wp);
            float4 hi4 = *(const float4*)(wp + 4);
            half8v f;
            f[0] = (_Float16)(lo.x  * sK[n]); f[1] = (_Float16)(lo.y  * sK[n]);
            f[2] = (_Float16)(lo.z  * sK[n]); f[3] = (_Float16)(lo.w  * sK[n]);
            f[4] = (_Float16)(hi4.x * sK[n]); f[5] = (_Float16)(hi4.y * sK[n]);
            f[6] = (_Float16)(hi4.z * sK[n]); f[7] = (_Float16)(hi4.w * sK[n]);
            bfrag[n][kk] = f;
        }
    }

    // fc weights aligned to this lane's A-frag k-slice
    float wfc0[8], wfc1[8];
#pragma unroll
    for (int j = 0; j < 8; ++j) { wfc0[j] = w_fc[8 * q + j]; wfc1[j] = w_fc[32 + 8 * q + j]; }
    const float bfc = b_fc[0];

    float cz = 0.f;               // cell state * K2 (batch q, unit 16w+c)
    const f32x4 zeroq = {0.f, 0.f, 0.f, 0.f};

    __syncthreads();

    half8v sa0 = {}, sa1 = {};  // saved A-frags for rotated fc-dot

    for (int tq = 0; tq < 128; ++tq) {
        // x for this lane's OWN batch (q), 4 steps (broadcast read)
        half4v xh = *(const half4v*)(&xls[q * XSTRIDE + tq * 4]);

#pragma unroll
        for (int dt = 0; dt < 4; ++dt) {
            const int t  = tq * 4 + dt;
            const int rb = t & 1;

            // A-frags: A[m][k] = h[m>>2][k]; lane row m=c -> LDS row c>>2
            const _Float16* hp = hbuf[rb] + (c >> 2) * HSTR + 8 * q;
            half8v a0 = *(const half8v*)(hp);        // k = 8q+j
            half8v a1 = *(const half8v*)(hp + 32);   // k = 32+8q+j

            if (dt == 0) {
                // pending fc-dot from previous tq, issued in the ds_read
                // latency shadow (independent of a0/a1). Saved frag was the
                // A of step stp = 4(tq-1)+w = h(stp-1) -> column stp-1.
                int stp = 4 * tq - 4 + w;
                if (tq > 0 && stp > 0) {
                    float s = out_dot(sa0, sa1, wfc0, wfc1);
                    if (lane < 16 && (lane & 3) == 0)
                        ols[(lane >> 2) * OSTRIDE + (stp - 1)] = s + bfc;
                }
            }

            if (dt == w) { sa0 = a0; sa1 = a1; }     // rotate fc-dot ownership

            // scalar x*wih+bias for the owned batch (off critical path)
            const float xv = (float)xh[dt];
            float xb[4];
#pragma unroll
            for (int n = 0; n < 4; ++n) xb[n] = fmaf(xv, wihS[n], biasS[n]);

            // gates: 4 class tiles, K=64 via chained MFMA pair, C = 0
            f32x4 acc[4];
#pragma unroll
            for (int n = 0; n < 4; ++n) {
                acc[n] = __builtin_amdgcn_mfma_f32_16x16x32_f16(a1, bfrag[n][1], zeroq, 0, 0, 0);
                acc[n] = __builtin_amdgcn_mfma_f32_16x16x32_f16(a0, bfrag[n][0], acc[n], 0, 0, 0);
            }

            // rows 4q..4q+3 are all batch q -> elem 0, no select needed
            float v0 = acc[0][0] + xb[0];
            float v1 = acc[1][0] + xb[1];
            float v2 = acc[2][0] + xb[2];
            float v3 = acc[3][0] + xb[3];

            // fused activations, cz = cs*K2 domain; lane owns (q, 16w+c)
            {
                float A   = ex2(v0);                    // e^{-i}
                float Bt  = ex2(v2);                    // e^{2g}
                float R   = rcp_fast((1.0f + A) * (1.0f + Bt));
                float pg  = fmaf(Bt, K2, -K2);          // (Bt-1)*K2
                float igk = pg * R;                     // i*g * K2
                float rf  = rcp_fast(1.0f + ex2(v1));   // sig(f)
                cz = fmaf(cz, rf, igk);
                float cc = fminf(fmaxf(cz, -CZCL), CZCL);
                float Ao = ex2(v3);                     // e^{-o}
                float C  = ex2(cc);                     // e^{2c}
                float h  = (C - 1.0f) * rcp_fast((1.0f + Ao) * (1.0f + C));
                hbuf[rb ^ 1][q * HSTR + 16 * w + c] = (_Float16)h;
            }
            __syncthreads();
        }
    }

    // epilogue pending fc-dot: saved frag from tq=127 -> st = 508+w,
    // column 507+w (covers 507..510)
    {
        float s = out_dot(sa0, sa1, wfc0, wfc1);
        if (lane < 16 && (lane & 3) == 0)
            ols[(lane >> 2) * OSTRIDE + (507 + w)] = s + bfc;
    }

    // final output column: h_511 lives in hbuf[0]
    if (w == 3) {
        const _Float16* hp = hbuf[0] + (c >> 2) * HSTR + 8 * q;
        half8v a0 = *(const half8v*)(hp);
        half8v a1 = *(const half8v*)(hp + 32);
        float s = out_dot(a0, a1, wfc0, wfc1);
        if (lane < 16 && (lane & 3) == 0)
            ols[(lane >> 2) * OSTRIDE + (T_STEPS - 1)] = s + bfc;
    }
    __syncthreads();

    // bulk store: LDS out -> global, coalesced
    for (int i = tid; i < NB * T_STEPS; i += 256) {
        int b = i >> 9;
        int t = i & (T_STEPS - 1);
        out[(size_t)(b0 + b) * T_STEPS + t] = ols[b * OSTRIDE + t];
    }
}

extern "C" void kernel_launch(void* const* d_in, const int* in_sizes, int n_in,
                              void* d_out, int out_size, void* d_ws, size_t ws_size,
                              hipStream_t stream) {
    const float* x    = (const float*)d_in[0];
    const float* w_ih = (const float*)d_in[1];
    const float* w_hh = (const float*)d_in[2];
    const float* b_ih = (const float*)d_in[3];
    const float* b_hh = (const float*)d_in[4];
    const float* w_fc = (const float*)d_in[5];
    const float* b_fc = (const float*)d_in[6];
    float* out = (float*)d_out;
    hipLaunchKernelGGL(lstm_kernel, dim3(2048 / NB), dim3(256), 0, stream,
                       x, w_ih, w_hh, b_ih, b_hh, w_fc, b_fc, out);
}